// Round 10
// baseline (115.636 us; speedup 1.0000x reference)
//
#include <hip/hip_runtime.h>
#include <hip/hip_cooperative_groups.h>
#include <cstdint>
#include <cstddef>

namespace cg = cooperative_groups;

// predictions: (16, 3, 160, 160, 9) fp32 -> per image N=76800 anchors x D=9
// targets:     (16, 32, 5) fp32 [cls, x, y, w, h]
// output: 4 fp32 scalars: total, box_loss, cls_loss, obj_loss
constexpr int kB     = 16;
constexpr int kN     = 76800;
constexpr int kD     = 9;
constexpr int kT     = 32;
constexpr int kBlk   = 256;            // threads/block; 4 anchors/thread/tile
constexpr int kApB   = 1024;           // anchors per tile
constexpr int kNB    = kN / kApB;      // 75 tiles per image
constexpr int kTPB   = 3;              // tiles per coop block
constexpr int kGX    = kNB / kTPB;     // 25 -> coop grid 25 x 16 = 400 blocks
constexpr int kWords = kN / 64;        // 1200 ballot words per image
constexpr int kCUs   = 256;            // MI355X

// jax.nn.softplus(x) == max(x,0) + log1p(exp(-|x|))
__device__ __forceinline__ float softplusf(float x) {
  return fmaxf(x, 0.f) + log1pf(expf(-fabsf(x)));
}

// ===========================================================================
// COOPERATIVE single-kernel path (400 blocks, 3 tiles each, 2 grid.sync).
// Needs only 2 blocks/CU co-resident -> safe for any VGPR<=256.
// ===========================================================================
__global__ __launch_bounds__(kBlk) void fused_kernel(
    const float* __restrict__ pred, const float* __restrict__ tgt,
    int* __restrict__ cnt, int* __restrict__ nnegA,
    float* __restrict__ objP, float* __restrict__ objN,
    unsigned long long* __restrict__ posBits,
    float* __restrict__ p3sq, float* __restrict__ p3ce,
    float* __restrict__ out)
{
  cg::grid_group grid = cg::this_grid();

  __shared__ float s_t1x[kT], s_t1y[kT], s_t2x[kT], s_t2y[kT], s_ta[kT];
  __shared__ float s_tx[kT], s_ty[kT];
  __shared__ int   s_tc[kT];
  __shared__ float s_red[4][2];
  __shared__ int   s_icnt[4][2];
  __shared__ int   s_ctot[4], s_pre[4];
  __shared__ float f3_sq[16][17], f3_ce[16][17], f3_op[16][17], f3_on[16][17];
  __shared__ int   f3_np[16][17], f3_nn[16][17];

  const int b    = blockIdx.y;
  const int blk  = blockIdx.x;           // 0..24
  const int tid  = threadIdx.x;
  const int lane = tid & 63;
  const int wv   = tid >> 6;

  // ---- targets -> LDS (pass0 fused; persists across grid.sync) ----
  if (tid < kT) {
    const float* tp = tgt + ((size_t)b * kT + tid) * 5;
    const float tx = tp[1], ty = tp[2], tw = tp[3], th = tp[4];
    const float t1x = tx - tw * 0.5f, t1y = ty - th * 0.5f;
    const float t2x = tx + tw * 0.5f, t2y = ty + th * 0.5f;
    s_t1x[tid] = t1x; s_t1y[tid] = t1y;
    s_t2x[tid] = t2x; s_t2y[tid] = t2y;
    s_ta[tid]  = (t2x - t1x) * (t2y - t1y);   // reference: prod(t2-t1)
    s_tx[tid] = tx; s_ty[tid] = ty;
    s_tc[tid] = (int)tp[0];
  }
  __syncthreads();

  // ---- Phase 1: 3 tiles x (4 anchors/thread, 8 aligned float4 loads) ----
  for (int t = 0; t < kTPB; ++t) {
    const int tile = blk + kGX * t;                  // 0..74
    const int a0 = tile * kApB + wv * 256 + 4 * lane;
    const float4* q = reinterpret_cast<const float4*>(
        pred + ((size_t)b * kN + a0) * kD);
    const float4 q0 = q[0], q1 = q[1], q2 = q[2], q3 = q[3];
    const float4 q4 = q[4], q5 = q[5], q6 = q[6], q7 = q[7];

    float px[4], py[4], pw_[4], ph[4], pobj[4];
    px[0]=q0.x; py[0]=q0.y; pw_[0]=q0.z; ph[0]=q0.w; pobj[0]=q1.x;
    px[1]=q2.y; py[1]=q2.z; pw_[1]=q2.w; ph[1]=q3.x; pobj[1]=q3.y;
    px[2]=q4.z; py[2]=q4.w; pw_[2]=q5.x; ph[2]=q5.y; pobj[2]=q5.z;
    px[3]=q6.w; py[3]=q7.x; pw_[3]=q7.y; ph[3]=q7.z; pobj[3]=q7.w;

    float p1x[4], p1y[4], p2x[4], p2y[4], pa[4];
    #pragma unroll
    for (int k = 0; k < 4; ++k) {
      p1x[k] = px[k] - pw_[k] * 0.5f;  p1y[k] = py[k] - ph[k] * 0.5f;
      p2x[k] = px[k] + pw_[k] * 0.5f;  p2y[k] = py[k] + ph[k] * 0.5f;
      pa[k]  = (p2x[k] - p1x[k]) * (p2y[k] - p1y[k]);
    }

    bool posA[4] = {false,false,false,false};
    bool negA[4] = {true,true,true,true};
    #pragma unroll
    for (int j = 0; j < kT; ++j) {
      const float t1x = s_t1x[j], t1y = s_t1y[j];
      const float t2x = s_t2x[j], t2y = s_t2y[j];
      const float ta  = s_ta[j];
      #pragma unroll
      for (int k = 0; k < 4; ++k) {
        const float lox = fmaxf(p1x[k], t1x), loy = fmaxf(p1y[k], t1y);
        const float hix = fminf(p2x[k], t2x), hiy = fminf(p2y[k], t2y);
        const float inter = fmaxf(hix - lox, 0.f) * fmaxf(hiy - loy, 0.f);
        const float d = ((pa[k] + ta) - inter) + 1e-6f; // reference eval order
        posA[k] = posA[k] || ((d >= 0.f) && (inter > 0.5f * d));
        negA[k] = negA[k] && ((d <  0.f) || (inter < 0.3f * d));
      }
    }

    float op = 0.f, on = 0.f;
    int pc = 0, nc = 0;
    const int chunk = tile * 4 + wv;
    #pragma unroll
    for (int k = 0; k < 4; ++k) {
      op += posA[k] ? softplusf(-pobj[k]) : 0.f;
      on += negA[k] ? softplusf( pobj[k]) : 0.f;
      const unsigned long long pm = __ballot(posA[k]);
      const unsigned long long nm = __ballot(negA[k]);
      if (lane == 0)
        posBits[(size_t)b * kWords + chunk * 4 + k] = pm;
      pc += __popcll(pm);
      nc += __popcll(nm);
    }

    #pragma unroll
    for (int off = 32; off > 0; off >>= 1) {
      op += __shfl_down(op, off, 64);
      on += __shfl_down(on, off, 64);
    }
    if (lane == 0) {
      s_red[wv][0] = op;  s_red[wv][1] = on;
      s_icnt[wv][0] = pc; s_icnt[wv][1] = nc;
    }
    __syncthreads();
    if (tid == 0) {
      float sop = 0.f, son = 0.f; int tpc = 0, tnc = 0;
      #pragma unroll
      for (int w = 0; w < 4; ++w) {
        sop += s_red[w][0]; son += s_red[w][1];
        tpc += s_icnt[w][0]; tnc += s_icnt[w][1];
      }
      const int slot = b * kNB + tile;
      cnt[slot]   = tpc;
      nnegA[slot] = tnc;
      objP[slot]  = sop;
      objN[slot]  = son;
    }
    __syncthreads();                                 // s_red reuse next tile
  }

  grid.sync();   // cnt + posBits visible grid-wide

  // ---- Phase 2: positives, 3 tiles (rank math validated R7/R8) ----
  for (int t = 0; t < kTPB; ++t) {
    const int tile = blk + kGX * t;
    const unsigned long long* wp =
        posBits + (size_t)b * kWords + (tile * 4 + wv) * 4;
    const unsigned long long m0 = wp[0], m1 = wp[1], m2 = wp[2], m3 = wp[3];
    const int ctot = __popcll(m0) + __popcll(m1) + __popcll(m2) + __popcll(m3);
    if (lane == 0) s_ctot[wv] = ctot;

    int c = (tid < tile) ? cnt[b * kNB + tid] : 0;   // tile <= 74 < 256
    #pragma unroll
    for (int off = 32; off > 0; off >>= 1) c += __shfl_down(c, off, 64);
    if (lane == 0) s_pre[wv] = c;
    __syncthreads();

    int base = 0;
    #pragma unroll
    for (int w = 0; w < 4; ++w) base += s_pre[w];
    for (int w = 0; w < wv; ++w) base += s_ctot[w];

    const unsigned long long low = ((unsigned long long)1 << lane) - 1ull;
    const int beforeLanes = __popcll(m0 & low) + __popcll(m1 & low)
                          + __popcll(m2 & low) + __popcll(m3 & low);
    const int kbit[4] = { (int)((m0 >> lane) & 1ull), (int)((m1 >> lane) & 1ull),
                          (int)((m2 >> lane) & 1ull), (int)((m3 >> lane) & 1ull) };

    const int a0 = tile * kApB + wv * 256 + 4 * lane;
    float sqc = 0.f, cec = 0.f;
    int prior = 0;
    #pragma unroll
    for (int k = 0; k < 4; ++k) {
      if (kbit[k]) {
        const int ord = base + beforeLanes + prior;
        const int tix = ord & (kT - 1);              // % 32
        const float* p = pred + ((size_t)b * kN + (a0 + k)) * kD;
        const float dx = p[0] - s_tx[tix];
        const float dy = p[1] - s_ty[tix];
        sqc += dx * dx + dy * dy;
        const float c0 = p[5], c1 = p[6], c2 = p[7], c3 = p[8];
        const float m = fmaxf(fmaxf(c0, c1), fmaxf(c2, c3));
        const float lse = m + logf(expf(c0 - m) + expf(c1 - m)
                                 + expf(c2 - m) + expf(c3 - m));
        const int tc = s_tc[tix];
        const float cv = (tc == 0) ? c0 : (tc == 1) ? c1 : (tc == 2) ? c2 : c3;
        cec += lse - cv;
      }
      prior += kbit[k];
    }

    #pragma unroll
    for (int off = 32; off > 0; off >>= 1) {
      sqc += __shfl_down(sqc, off, 64);
      cec += __shfl_down(cec, off, 64);
    }
    if (lane == 0) { s_red[wv][0] = sqc; s_red[wv][1] = cec; }
    __syncthreads();
    if (tid == 0) {
      float ss = 0.f, cs = 0.f;
      #pragma unroll
      for (int w = 0; w < 4; ++w) { ss += s_red[w][0]; cs += s_red[w][1]; }
      const int slot = b * kNB + tile;
      p3sq[slot] = ss;
      p3ce[slot] = cs;
    }
    __syncthreads();
  }

  grid.sync();   // all partials visible

  // ---- Phase 3: block (0,0) reduces 1200 slots x 6 arrays ----
  if (blk == 0 && b == 0) {
    const int ib = tid & 15, g = tid >> 4;
    int   np = 0, nn = 0;
    float top_ = 0.f, ton_ = 0.f, sq = 0.f, ce = 0.f;
    for (int k = g; k < kNB; k += 16) {
      const int s = ib * kNB + k;
      np += cnt[s];    nn += nnegA[s];
      top_ += objP[s]; ton_ += objN[s];
      sq += p3sq[s];   ce += p3ce[s];
    }
    f3_np[g][ib] = np;   f3_nn[g][ib] = nn;
    f3_op[g][ib] = top_; f3_on[g][ib] = ton_;
    f3_sq[g][ib] = sq;   f3_ce[g][ib] = ce;
    __syncthreads();

    float box = 0.f, cls = 0.f, obj = 0.f;
    if (tid < kB) {
      int tnp = 0, tnn = 0;
      float sop = 0.f, son = 0.f, tsq = 0.f, tce = 0.f;
      #pragma unroll
      for (int gg = 0; gg < 16; ++gg) {
        tnp += f3_np[gg][tid]; tnn += f3_nn[gg][tid];
        sop += f3_op[gg][tid]; son += f3_on[gg][tid];
        tsq += f3_sq[gg][tid]; tce += f3_ce[gg][tid];
      }
      const float np_ = (float)tnp;
      const float nn_ = (float)tnn;
      if (np_ > 0.f) {
        box = tsq / (2.0f * np_);
        cls = tce / np_;
        obj = sop / np_;
      }
      if (nn_ > 0.f) obj += son / nn_;
    }
    #pragma unroll
    for (int off = 8; off > 0; off >>= 1) {
      box += __shfl_down(box, off, 64);
      cls += __shfl_down(cls, off, 64);
      obj += __shfl_down(obj, off, 64);
    }
    if (tid == 0) {
      box *= (1.f / 16.f); cls *= (1.f / 16.f); obj *= (1.f / 16.f);
      out[0] = 0.05f * box + 0.5f * cls + 1.0f * obj;
      out[1] = box;
      out[2] = cls;
      out[3] = obj;
    }
  }
}

// ===========================================================================
// FALLBACK path: R8's 4-kernel pipeline, verbatim (115.1 us, absmax 0.0).
// ===========================================================================
__global__ __launch_bounds__(kB * kT) void pass0_kernel(
    const float* __restrict__ tgt, float* __restrict__ twork)
{
  const int t = threadIdx.x;
  const int b = t >> 5, j = t & 31;
  const float* tp = tgt + ((size_t)b * kT + j) * 5;
  const float tx = tp[1], ty = tp[2], tw = tp[3], th = tp[4];
  const float t1x = tx - tw * 0.5f, t1y = ty - th * 0.5f;
  const float t2x = tx + tw * 0.5f, t2y = ty + th * 0.5f;
  float* w = twork + (size_t)b * 5 * kT;
  w[0 * kT + j] = t1x;
  w[1 * kT + j] = t1y;
  w[2 * kT + j] = t2x;
  w[3 * kT + j] = t2y;
  w[4 * kT + j] = (t2x - t1x) * (t2y - t1y);
}

__global__ __launch_bounds__(kBlk) void k1_iou_kernel(
    const float* __restrict__ pred, const float* __restrict__ twork,
    int* __restrict__ cnt, int* __restrict__ nnegA,
    float* __restrict__ objP, float* __restrict__ objN,
    unsigned long long* __restrict__ posBits)
{
  __shared__ float s_red[4][2];
  __shared__ int   s_cnt[4][2];

  const int b    = blockIdx.y;
  const int blk  = blockIdx.x;
  const int tid  = threadIdx.x;
  const int lane = tid & 63;
  const int wv   = tid >> 6;
  const float* tw = twork + (size_t)b * 5 * kT;

  const int a0 = blk * kApB + wv * 256 + 4 * lane;
  const float4* q = reinterpret_cast<const float4*>(
      pred + ((size_t)b * kN + a0) * kD);
  const float4 q0 = q[0], q1 = q[1], q2 = q[2], q3 = q[3];
  const float4 q4 = q[4], q5 = q[5], q6 = q[6], q7 = q[7];

  float px[4], py[4], pw_[4], ph[4], pobj[4];
  px[0]=q0.x; py[0]=q0.y; pw_[0]=q0.z; ph[0]=q0.w; pobj[0]=q1.x;
  px[1]=q2.y; py[1]=q2.z; pw_[1]=q2.w; ph[1]=q3.x; pobj[1]=q3.y;
  px[2]=q4.z; py[2]=q4.w; pw_[2]=q5.x; ph[2]=q5.y; pobj[2]=q5.z;
  px[3]=q6.w; py[3]=q7.x; pw_[3]=q7.y; ph[3]=q7.z; pobj[3]=q7.w;

  float p1x[4], p1y[4], p2x[4], p2y[4], pa[4];
  #pragma unroll
  for (int k = 0; k < 4; ++k) {
    p1x[k] = px[k] - pw_[k] * 0.5f;  p1y[k] = py[k] - ph[k] * 0.5f;
    p2x[k] = px[k] + pw_[k] * 0.5f;  p2y[k] = py[k] + ph[k] * 0.5f;
    pa[k]  = (p2x[k] - p1x[k]) * (p2y[k] - p1y[k]);
  }

  bool posA[4] = {false,false,false,false};
  bool negA[4] = {true,true,true,true};
  #pragma unroll
  for (int j = 0; j < kT; ++j) {
    const float t1x = tw[0 * kT + j], t1y = tw[1 * kT + j];
    const float t2x = tw[2 * kT + j], t2y = tw[3 * kT + j];
    const float ta  = tw[4 * kT + j];
    #pragma unroll
    for (int k = 0; k < 4; ++k) {
      const float lox = fmaxf(p1x[k], t1x), loy = fmaxf(p1y[k], t1y);
      const float hix = fminf(p2x[k], t2x), hiy = fminf(p2y[k], t2y);
      const float inter = fmaxf(hix - lox, 0.f) * fmaxf(hiy - loy, 0.f);
      const float d = ((pa[k] + ta) - inter) + 1e-6f;
      posA[k] = posA[k] || ((d >= 0.f) && (inter > 0.5f * d));
      negA[k] = negA[k] && ((d <  0.f) || (inter < 0.3f * d));
    }
  }

  float op = 0.f, on = 0.f;
  int pc = 0, nc = 0;
  const int chunk = blk * 4 + wv;
  #pragma unroll
  for (int k = 0; k < 4; ++k) {
    op += posA[k] ? softplusf(-pobj[k]) : 0.f;
    on += negA[k] ? softplusf( pobj[k]) : 0.f;
    const unsigned long long pm = __ballot(posA[k]);
    const unsigned long long nm = __ballot(negA[k]);
    if (lane == 0)
      posBits[(size_t)b * kWords + chunk * 4 + k] = pm;
    pc += __popcll(pm);
    nc += __popcll(nm);
  }

  #pragma unroll
  for (int off = 32; off > 0; off >>= 1) {
    op += __shfl_down(op, off, 64);
    on += __shfl_down(on, off, 64);
  }
  if (lane == 0) {
    s_red[wv][0] = op;  s_red[wv][1] = on;
    s_cnt[wv][0] = pc;  s_cnt[wv][1] = nc;
  }
  __syncthreads();
  if (tid == 0) {
    float sop = 0.f, son = 0.f; int tpc = 0, tnc = 0;
    #pragma unroll
    for (int w = 0; w < 4; ++w) {
      sop += s_red[w][0]; son += s_red[w][1];
      tpc += s_cnt[w][0]; tnc += s_cnt[w][1];
    }
    const int slot = b * kNB + blk;
    cnt[slot]   = tpc;
    nnegA[slot] = tnc;
    objP[slot]  = sop;
    objN[slot]  = son;
  }
}

__global__ __launch_bounds__(kBlk) void k2_pos_kernel(
    const float* __restrict__ pred, const float* __restrict__ tgt,
    const int* __restrict__ cnt,
    const unsigned long long* __restrict__ posBits,
    float* __restrict__ p3sq, float* __restrict__ p3ce)
{
  __shared__ float s_tx[kT], s_ty[kT];
  __shared__ int   s_tc[kT];
  __shared__ int   s_ctot[4];
  __shared__ int   s_pre[4];
  __shared__ float s_red[4][2];

  const int b = blockIdx.y, blk = blockIdx.x, tid = threadIdx.x;
  const int slot = b * kNB + blk;
  const int lane = tid & 63, wv = tid >> 6;

  const unsigned long long* wp =
      posBits + (size_t)b * kWords + (blk * 4 + wv) * 4;
  const unsigned long long m0 = wp[0], m1 = wp[1], m2 = wp[2], m3 = wp[3];
  const int ctot = __popcll(m0) + __popcll(m1) + __popcll(m2) + __popcll(m3);
  if (lane == 0) s_ctot[wv] = ctot;

  int c = (tid < blk) ? cnt[b * kNB + tid] : 0;
  #pragma unroll
  for (int off = 32; off > 0; off >>= 1) c += __shfl_down(c, off, 64);
  if (lane == 0) s_pre[wv] = c;

  if (tid < kT) {
    const float* tp = tgt + ((size_t)b * kT + tid) * 5;
    s_tx[tid] = tp[1]; s_ty[tid] = tp[2];
    s_tc[tid] = (int)tp[0];
  }
  __syncthreads();

  int tot = 0, base = 0;
  #pragma unroll
  for (int w = 0; w < 4; ++w) { tot += s_ctot[w]; base += s_pre[w]; }
  if (tot == 0) {
    if (tid == 0) { p3sq[slot] = 0.f; p3ce[slot] = 0.f; }
    return;
  }
  for (int w = 0; w < wv; ++w) base += s_ctot[w];

  const unsigned long long low = ((unsigned long long)1 << lane) - 1ull;
  const int beforeLanes = __popcll(m0 & low) + __popcll(m1 & low)
                        + __popcll(m2 & low) + __popcll(m3 & low);
  const int kbit[4] = { (int)((m0 >> lane) & 1ull), (int)((m1 >> lane) & 1ull),
                        (int)((m2 >> lane) & 1ull), (int)((m3 >> lane) & 1ull) };

  const int a0 = blk * kApB + wv * 256 + 4 * lane;
  float sqc = 0.f, cec = 0.f;
  int prior = 0;
  #pragma unroll
  for (int k = 0; k < 4; ++k) {
    if (kbit[k]) {
      const int ord = base + beforeLanes + prior;
      const int tix = ord & (kT - 1);
      const float* p = pred + ((size_t)b * kN + (a0 + k)) * kD;
      const float dx = p[0] - s_tx[tix];
      const float dy = p[1] - s_ty[tix];
      sqc += dx * dx + dy * dy;
      const float c0 = p[5], c1 = p[6], c2 = p[7], c3 = p[8];
      const float m = fmaxf(fmaxf(c0, c1), fmaxf(c2, c3));
      const float lse = m + logf(expf(c0 - m) + expf(c1 - m)
                               + expf(c2 - m) + expf(c3 - m));
      const int tc = s_tc[tix];
      const float cv = (tc == 0) ? c0 : (tc == 1) ? c1 : (tc == 2) ? c2 : c3;
      cec += lse - cv;
    }
    prior += kbit[k];
  }

  #pragma unroll
  for (int off = 32; off > 0; off >>= 1) {
    sqc += __shfl_down(sqc, off, 64);
    cec += __shfl_down(cec, off, 64);
  }
  if (lane == 0) { s_red[wv][0] = sqc; s_red[wv][1] = cec; }
  __syncthreads();
  if (tid == 0) {
    float ss = 0.f, cs = 0.f;
    #pragma unroll
    for (int w = 0; w < 4; ++w) { ss += s_red[w][0]; cs += s_red[w][1]; }
    p3sq[slot] = ss;
    p3ce[slot] = cs;
  }
}

__global__ __launch_bounds__(kBlk) void k3_final_kernel(
    const int* __restrict__ cnt, const int* __restrict__ nnegA,
    const float* __restrict__ objP, const float* __restrict__ objN,
    const float* __restrict__ p3sq, const float* __restrict__ p3ce,
    float* __restrict__ out)
{
  __shared__ float s_sq[16][17], s_ce[16][17], s_op[16][17], s_on[16][17];
  __shared__ int   s_np[16][17], s_nn[16][17];
  const int tid = threadIdx.x;
  const int b = tid & 15, g = tid >> 4;
  int   np = 0, nn = 0;
  float op = 0.f, on = 0.f, sq = 0.f, ce = 0.f;
  for (int k = g; k < kNB; k += 16) {
    const int s = b * kNB + k;
    np += cnt[s];  nn += nnegA[s];
    op += objP[s]; on += objN[s];
    sq += p3sq[s]; ce += p3ce[s];
  }
  s_np[g][b] = np; s_nn[g][b] = nn;
  s_op[g][b] = op; s_on[g][b] = on;
  s_sq[g][b] = sq; s_ce[g][b] = ce;
  __syncthreads();

  float box = 0.f, cls = 0.f, obj = 0.f;
  if (tid < kB) {
    int tnp = 0, tnn = 0;
    float top = 0.f, ton = 0.f, tsq = 0.f, tce = 0.f;
    #pragma unroll
    for (int gg = 0; gg < 16; ++gg) {
      tnp += s_np[gg][tid]; tnn += s_nn[gg][tid];
      top += s_op[gg][tid]; ton += s_on[gg][tid];
      tsq += s_sq[gg][tid]; tce += s_ce[gg][tid];
    }
    const float np_ = (float)tnp;
    const float nn_ = (float)tnn;
    if (np_ > 0.f) {
      box = tsq / (2.0f * np_);
      cls = tce / np_;
      obj = top / np_;
    }
    if (nn_ > 0.f) obj += ton / nn_;
  }
  #pragma unroll
  for (int off = 8; off > 0; off >>= 1) {
    box += __shfl_down(box, off, 64);
    cls += __shfl_down(cls, off, 64);
    obj += __shfl_down(obj, off, 64);
  }
  if (tid == 0) {
    box *= (1.f / 16.f); cls *= (1.f / 16.f); obj *= (1.f / 16.f);
    out[0] = 0.05f * box + 0.5f * cls + 1.0f * obj;
    out[1] = box;
    out[2] = cls;
    out[3] = obj;
  }
}

// ---------------------------------------------------------------------------
extern "C" void kernel_launch(void* const* d_in, const int* in_sizes, int n_in,
                              void* d_out, int out_size, void* d_ws, size_t ws_size,
                              hipStream_t stream)
{
  const float* pred = (const float*)d_in[0];
  const float* tgt  = (const float*)d_in[1];
  float* out = (float*)d_out;

  char* ws = (char*)d_ws;
  int*   cnt   = (int*)(ws);                         // 4800 B (pad 64B)
  int*   nnegA = (int*)(ws + 4864);
  float* objP  = (float*)(ws + 9728);
  float* objN  = (float*)(ws + 14592);
  float* p3sq  = (float*)(ws + 19456);
  float* p3ce  = (float*)(ws + 24320);
  unsigned long long* posBits =
      (unsigned long long*)(ws + 29184);             // 153600 B
  float* twork = (float*)(ws + 182784);              // 10240 B (fallback only)

  // Host-only occupancy query (graph-capture safe): coop needs 400 blocks.
  int maxPerCU = 0;
  hipError_t qe = hipOccupancyMaxActiveBlocksPerMultiprocessor(
      &maxPerCU, (const void*)fused_kernel, kBlk, 0);
  bool coop_ok = (qe == hipSuccess) && (maxPerCU * kCUs >= kGX * kB);

  if (coop_ok) {
    void* args[] = { (void*)&pred, (void*)&tgt, (void*)&cnt, (void*)&nnegA,
                     (void*)&objP, (void*)&objN, (void*)&posBits,
                     (void*)&p3sq, (void*)&p3ce, (void*)&out };
    hipError_t le = hipLaunchCooperativeKernel(
        (const void*)fused_kernel, dim3(kGX, kB), dim3(kBlk), args, 0, stream);
    if (le == hipSuccess) return;
  }

  // Fallback: R8 4-kernel pipeline (proven 115.1 us, absmax 0.0).
  pass0_kernel<<<1, kB * kT, 0, stream>>>(tgt, twork);
  k1_iou_kernel<<<dim3(kNB, kB), kBlk, 0, stream>>>(
      pred, twork, cnt, nnegA, objP, objN, posBits);
  k2_pos_kernel<<<dim3(kNB, kB), kBlk, 0, stream>>>(
      pred, tgt, cnt, posBits, p3sq, p3ce);
  k3_final_kernel<<<1, kBlk, 0, stream>>>(
      cnt, nnegA, objP, objN, p3sq, p3ce, out);
}